// Round 2
// baseline (291.119 us; speedup 1.0000x reference)
//
#include <hip/hip_runtime.h>
#include <cstdint>

#define B_  8
#define S_  2048
#define E_  1024
#define H_  128
#define NC_ 16          // chunks per sequence (S_/128)

typedef __attribute__((ext_vector_type(8))) short bf16x8;
typedef __attribute__((ext_vector_type(4))) float f32x4;

__device__ __forceinline__ short f2bf(float f){
  uint32_t u = __builtin_bit_cast(uint32_t, f);
  u = (u + 0x7fffu + ((u >> 16) & 1u)) >> 16;   // RNE
  return (short)u;
}
__device__ __forceinline__ float bf2f(short s){
  uint32_t u = ((uint32_t)(uint16_t)s) << 16;
  return __builtin_bit_cast(float, u);
}
__device__ __forceinline__ void load_lds16(const void* g, void* l){
  __builtin_amdgcn_global_load_lds(
    (const __attribute__((address_space(1))) void*)g,
    (__attribute__((address_space(3))) void*)l, 16, 0, 0);
}

// ---------------------------------------------------------------------------
// Kernel 1: W (E,H) f32 -> Wt (H,E) bf16, LDS-tiled transpose
// ---------------------------------------------------------------------------
__global__ __launch_bounds__(256) void wt_kernel(
    const float* __restrict__ WQ, const float* __restrict__ WK,
    const float* __restrict__ WV,
    short* __restrict__ WtQ, short* __restrict__ WtK, short* __restrict__ WtV)
{
  int which = blockIdx.z;
  const float* W = which == 0 ? WQ : which == 1 ? WK : WV;
  short* Wt      = which == 0 ? WtQ : which == 1 ? WtK : WtV;
  int k0 = blockIdx.x * 32, n0 = blockIdx.y * 32;
  __shared__ float t[32][33];
  int tx = threadIdx.x & 31, ty = threadIdx.x >> 5;
  #pragma unroll
  for (int i = 0; i < 4; i++)
    t[ty + i * 8][tx] = W[(size_t)(k0 + ty + i * 8) * H_ + n0 + tx];
  __syncthreads();
  #pragma unroll
  for (int i = 0; i < 4; i++)
    Wt[(size_t)(n0 + ty + i * 8) * E_ + k0 + tx] = f2bf(t[tx][ty + i * 8]);
}

// ---------------------------------------------------------------------------
// Kernel 2: projections P = X @ W, barrier-free streaming MFMA.
// Wave owns 16 rows x 128 cols. A (f32) direct from global -> convert bf16;
// B (bf16, 256KB, L2-resident) direct from global. No LDS, no __syncthreads.
// ---------------------------------------------------------------------------
__global__ __launch_bounds__(256) void proj_kernel(
    const float* __restrict__ Xq, const float* __restrict__ Xk,
    const float* __restrict__ Xv,
    const short* __restrict__ Wtq, const short* __restrict__ Wtk,
    const short* __restrict__ Wtv,
    short* __restrict__ Pq, short* __restrict__ Pk, short* __restrict__ Pv)
{
  int which = blockIdx.y;
  const float* X  = which == 0 ? Xq  : which == 1 ? Xk  : Xv;
  const short* Wt = which == 0 ? Wtq : which == 1 ? Wtk : Wtv;
  short* P        = which == 0 ? Pq  : which == 1 ? Pk  : Pv;

  int tid = threadIdx.x, lane = tid & 63, wave = tid >> 6;
  int lr = lane & 15, lq = lane >> 4;
  int rowbase = blockIdx.x * 64 + wave * 16;

  const float* xr = X + (size_t)(rowbase + lr) * E_ + lq * 8;
  const short* wb = Wt + (size_t)lr * E_ + lq * 8;

  f32x4 acc[8];
  #pragma unroll
  for (int tn = 0; tn < 8; tn++) acc[tn] = (f32x4){0.f, 0.f, 0.f, 0.f};

  f32x4 alo = *(const f32x4*)xr;
  f32x4 ahi = *(const f32x4*)(xr + 4);
  bf16x8 bfr[8];
  #pragma unroll
  for (int tn = 0; tn < 8; tn++)
    bfr[tn] = *(const bf16x8*)(wb + (size_t)tn * 16 * E_);

  #pragma unroll 4
  for (int k0 = 32; k0 <= E_; k0 += 32){
    // convert current A stage
    bf16x8 a;
    #pragma unroll
    for (int j = 0; j < 4; j++){ a[j] = f2bf(alo[j]); a[4 + j] = f2bf(ahi[j]); }
    bf16x8 bc[8];
    #pragma unroll
    for (int tn = 0; tn < 8; tn++) bc[tn] = bfr[tn];
    // prefetch next stage (wave-uniform branch)
    if (k0 < E_){
      alo = *(const f32x4*)(xr + k0);
      ahi = *(const f32x4*)(xr + k0 + 4);
      #pragma unroll
      for (int tn = 0; tn < 8; tn++)
        bfr[tn] = *(const bf16x8*)(wb + (size_t)tn * 16 * E_ + k0);
    }
    #pragma unroll
    for (int tn = 0; tn < 8; tn++)
      acc[tn] = __builtin_amdgcn_mfma_f32_16x16x32_bf16(a, bc[tn], acc[tn], 0, 0, 0);
  }

  // epilogue: C/D layout col=lane&15, row=(lane>>4)*4+reg
  #pragma unroll
  for (int tn = 0; tn < 8; tn++)
    #pragma unroll
    for (int r4 = 0; r4 < 4; r4++){
      int row = rowbase + lq * 4 + r4;
      int col = tn * 16 + lr;
      P[(size_t)row * H_ + col] = f2bf(acc[tn][r4]);
    }
}

// ---------------------------------------------------------------------------
// Kernel 3: transpose k,v (B,S,H) -> kT,vT (B,H,S), bf16, 32x32 LDS tiles
// ---------------------------------------------------------------------------
__global__ __launch_bounds__(256) void transpose2(
    const short* __restrict__ k, const short* __restrict__ v,
    short* __restrict__ kT, short* __restrict__ vT)
{
  int b = blockIdx.z & 7;
  int which = blockIdx.z >> 3;
  const short* src = which ? v : k;
  short* dst       = which ? vT : kT;
  src += (size_t)b * S_ * H_;
  dst += (size_t)b * H_ * S_;
  int s0 = blockIdx.x * 32, h0 = blockIdx.y * 32;

  __shared__ short t[32][33];
  int tx = threadIdx.x & 31, ty = threadIdx.x >> 5;
  #pragma unroll
  for (int i = 0; i < 4; i++)
    t[ty + i * 8][tx] = src[(size_t)(s0 + ty + i * 8) * H_ + h0 + tx];
  __syncthreads();
  #pragma unroll
  for (int i = 0; i < 4; i++)
    dst[(size_t)(h0 + ty + i * 8) * S_ + s0 + tx] = t[tx][ty + i * 8];
}

// ---------------------------------------------------------------------------
// Kernel 4: per-chunk state M_j[h'][h] = sum_t V[t][h'] K[t][h]   (f32 out)
// ---------------------------------------------------------------------------
__global__ __launch_bounds__(256) void chunk_state(
    const short* __restrict__ vT, const short* __restrict__ kT,
    float* __restrict__ M)
{
  int j = blockIdx.x, b = blockIdx.y;
  int tid = threadIdx.x, lane = tid & 63, wave = tid >> 6;
  int wrow = (wave >> 1) * 64, wcol = (wave & 1) * 64;
  int lr = lane & 15, lq = lane >> 4;

  __shared__ short As[128 * 32];
  __shared__ short Bs[128 * 32];

  const short* vtb = vT + (size_t)b * H_ * S_ + j * 128;
  const short* ktb = kT + (size_t)b * H_ * S_ + j * 128;

  f32x4 acc[4][4];
  #pragma unroll
  for (int a = 0; a < 4; a++)
    #pragma unroll
    for (int c = 0; c < 4; c++) acc[a][c] = (f32x4){0.f, 0.f, 0.f, 0.f};

  for (int t0 = 0; t0 < 128; t0 += 32){
    __syncthreads();
    #pragma unroll
    for (int i = 0; i < 2; i++){
      int r = wave * 32 + i * 16 + (lane >> 2);
      int c = (lane & 3) * 8;
      load_lds16(vtb + (size_t)r * S_ + t0 + c,
                 (void*)(As + (wave * 32 + i * 16) * 32));
      load_lds16(ktb + (size_t)r * S_ + t0 + c,
                 (void*)(Bs + (wave * 32 + i * 16) * 32));
    }
    __syncthreads();
    bf16x8 af[4], bf[4];
    #pragma unroll
    for (int tm = 0; tm < 4; tm++)
      af[tm] = *(const bf16x8*)(As + (wrow + tm * 16 + lr) * 32 + lq * 8);
    #pragma unroll
    for (int tn = 0; tn < 4; tn++)
      bf[tn] = *(const bf16x8*)(Bs + (wcol + tn * 16 + lr) * 32 + lq * 8);
    #pragma unroll
    for (int tm = 0; tm < 4; tm++)
      #pragma unroll
      for (int tn = 0; tn < 4; tn++)
        acc[tm][tn] = __builtin_amdgcn_mfma_f32_16x16x32_bf16(
            af[tm], bf[tn], acc[tm][tn], 0, 0, 0);
  }

  float* mb = M + (size_t)(b * NC_ + j) * 16384;
  #pragma unroll
  for (int tm = 0; tm < 4; tm++)
    #pragma unroll
    for (int tn = 0; tn < 4; tn++)
      #pragma unroll
      for (int r4 = 0; r4 < 4; r4++){
        int row = wrow + tm * 16 + lq * 4 + r4;
        int col = wcol + tn * 16 + lr;
        mb[row * 128 + col] = acc[tm][tn][r4];
      }
}

// ---------------------------------------------------------------------------
// Kernel 5: exclusive prefix of M over chunks -> bf16 hi + residual lo.
// All 16 chunk values prefetched (independent loads) before the serial sum.
// ---------------------------------------------------------------------------
__global__ __launch_bounds__(256) void prefix_state(
    const float* __restrict__ M, short* __restrict__ Shi, short* __restrict__ Slo)
{
  int b = blockIdx.y;
  int idx = (blockIdx.x * 256 + threadIdx.x) * 4;
  float4 mv[NC_];
  #pragma unroll
  for (int j = 0; j < NC_; j++)
    mv[j] = *(const float4*)(M + (size_t)(b * NC_ + j) * 16384 + idx);

  float r0 = 0.f, r1 = 0.f, r2 = 0.f, r3 = 0.f;
  #pragma unroll
  for (int j = 0; j < NC_; j++){
    size_t o = (size_t)(b * NC_ + j) * 16384 + idx;
    short h0 = f2bf(r0), h1 = f2bf(r1), h2 = f2bf(r2), h3 = f2bf(r3);
    short l0 = f2bf(r0 - bf2f(h0)), l1 = f2bf(r1 - bf2f(h1));
    short l2 = f2bf(r2 - bf2f(h2)), l3 = f2bf(r3 - bf2f(h3));
    union { short s[4]; uint2 u; } ph, pl;
    ph.s[0] = h0; ph.s[1] = h1; ph.s[2] = h2; ph.s[3] = h3;
    pl.s[0] = l0; pl.s[1] = l1; pl.s[2] = l2; pl.s[3] = l3;
    *(uint2*)(Shi + o) = ph.u;
    *(uint2*)(Slo + o) = pl.u;
    r0 += mv[j].x; r1 += mv[j].y; r2 += mv[j].z; r3 += mv[j].w;
  }
}

// ---------------------------------------------------------------------------
// Kernel 6: per (b, chunk i, row-half): 64 rows of
//   O = (Q_i K_i^T . tril) V_i + Q_i (State_hi + State_lo)
// ---------------------------------------------------------------------------
__global__ __launch_bounds__(256) void passC(
    const short* __restrict__ qb, const short* __restrict__ kb,
    const short* __restrict__ vT, const short* __restrict__ Shi,
    const short* __restrict__ Slo, float* __restrict__ out)
{
  int i = blockIdx.x, half = blockIdx.y, b = blockIdx.z;
  int roff = half * 64;
  int tid = threadIdx.x, lane = tid & 63, wave = tid >> 6;
  int wrow = (wave >> 1) * 32, wcol = (wave & 1) * 64;
  int lr = lane & 15, lq = lane >> 4;

  __shared__ short Qs[64 * 136];    // padded stride 136
  __shared__ short Ss[64 * 136];
  __shared__ short Bsh[128 * 32];   // DMA staging (unpadded)

  const short* qbase = qb + ((size_t)b * S_ + i * 128 + roff) * H_;
  const short* kbase = kb + ((size_t)b * S_ + i * 128) * H_;
  const short* vtb   = vT + (size_t)b * H_ * S_ + i * 128;
  const short* shib  = Shi + (size_t)(b * NC_ + i) * 16384;
  const short* slob  = Slo + (size_t)(b * NC_ + i) * 16384;

  // stage 64 Q rows into padded LDS
  #pragma unroll
  for (int t = 0; t < 4; t++){
    int chunk = t * 256 + tid;           // 1024 chunks of 16B
    int s = chunk >> 4, c16 = chunk & 15;
    *(uint4*)(Qs + s * 136 + c16 * 8) =
        *(const uint4*)(qbase + s * H_ + c16 * 8);
  }

  f32x4 acc[2][4];
  #pragma unroll
  for (int a = 0; a < 2; a++)
    #pragma unroll
    for (int c = 0; c < 4; c++) acc[a][c] = (f32x4){0.f, 0.f, 0.f, 0.f};

  // ---- phase 1: S = Q_half K^T (k-dim = h) ----
  for (int h0 = 0; h0 < H_; h0 += 32){
    __syncthreads();
    #pragma unroll
    for (int t = 0; t < 2; t++){
      int r = wave * 32 + t * 16 + (lane >> 2);
      int c = (lane & 3) * 8;
      load_lds16(kbase + (size_t)r * H_ + h0 + c,
                 (void*)(Bsh + (wave * 32 + t * 16) * 32));
    }
    __syncthreads();
    bf16x8 af[2], bf[4];
    #pragma unroll
    for (int tm = 0; tm < 2; tm++)
      af[tm] = *(const bf16x8*)(Qs + (wrow + tm * 16 + lr) * 136 + h0 + lq * 8);
    #pragma unroll
    for (int tn = 0; tn < 4; tn++)
      bf[tn] = *(const bf16x8*)(Bsh + (wcol + tn * 16 + lr) * 32 + lq * 8);
    #pragma unroll
    for (int tm = 0; tm < 2; tm++)
      #pragma unroll
      for (int tn = 0; tn < 4; tn++)
        acc[tm][tn] = __builtin_amdgcn_mfma_f32_16x16x32_bf16(
            af[tm], bf[tn], acc[tm][tn], 0, 0, 0);
  }
  __syncthreads();

  // ---- phase 2: causal mask + bf16 -> Ss; zero acc for O ----
  #pragma unroll
  for (int tm = 0; tm < 2; tm++)
    #pragma unroll
    for (int tn = 0; tn < 4; tn++)
      #pragma unroll
      for (int r4 = 0; r4 < 4; r4++){
        int row = wrow + tm * 16 + lq * 4 + r4;     // local row in half
        int col = wcol + tn * 16 + lr;              // t index 0..127
        float vv = (col <= roff + row) ? acc[tm][tn][r4] : 0.f;
        Ss[row * 136 + col] = f2bf(vv);
      }
  #pragma unroll
  for (int a = 0; a < 2; a++)
    #pragma unroll
    for (int c = 0; c < 4; c++) acc[a][c] = (f32x4){0.f, 0.f, 0.f, 0.f};
  __syncthreads();

  // ---- phase 3a: O += S V (k-dim = t); B operand from vT rows ----
  for (int t0 = 0; t0 < 128; t0 += 32){
    __syncthreads();
    #pragma unroll
    for (int t = 0; t < 2; t++){
      int r = wave * 32 + t * 16 + (lane >> 2);
      int c = (lane & 3) * 8;
      load_lds16(vtb + (size_t)r * S_ + t0 + c,
                 (void*)(Bsh + (wave * 32 + t * 16) * 32));
    }
    __syncthreads();
    bf16x8 af[2], bf[4];
    #pragma unroll
    for (int tm = 0; tm < 2; tm++)
      af[tm] = *(const bf16x8*)(Ss + (wrow + tm * 16 + lr) * 136 + t0 + lq * 8);
    #pragma unroll
    for (int tn = 0; tn < 4; tn++)
      bf[tn] = *(const bf16x8*)(Bsh + (wcol + tn * 16 + lr) * 32 + lq * 8);
    #pragma unroll
    for (int tm = 0; tm < 2; tm++)
      #pragma unroll
      for (int tn = 0; tn < 4; tn++)
        acc[tm][tn] = __builtin_amdgcn_mfma_f32_16x16x32_bf16(
            af[tm], bf[tn], acc[tm][tn], 0, 0, 0);
  }

  // ---- phase 3b: O += Q * State (hi then lo residual), k-dim = h ----
  #pragma unroll
  for (int part = 0; part < 2; part++){
    const short* sb = part == 0 ? shib : slob;
    for (int h0 = 0; h0 < H_; h0 += 32){
      __syncthreads();
      #pragma unroll
      for (int t = 0; t < 2; t++){
        int r = wave * 32 + t * 16 + (lane >> 2);
        int c = (lane & 3) * 8;
        load_lds16(sb + (size_t)r * 128 + h0 + c,
                   (void*)(Bsh + (wave * 32 + t * 16) * 32));
      }
      __syncthreads();
      bf16x8 af[2], bf[4];
      #pragma unroll
      for (int tm = 0; tm < 2; tm++)
        af[tm] = *(const bf16x8*)(Qs + (wrow + tm * 16 + lr) * 136 + h0 + lq * 8);
      #pragma unroll
      for (int tn = 0; tn < 4; tn++)
        bf[tn] = *(const bf16x8*)(Bsh + (wcol + tn * 16 + lr) * 32 + lq * 8);
      #pragma unroll
      for (int tm = 0; tm < 2; tm++)
        #pragma unroll
        for (int tn = 0; tn < 4; tn++)
          acc[tm][tn] = __builtin_amdgcn_mfma_f32_16x16x32_bf16(
              af[tm], bf[tn], acc[tm][tn], 0, 0, 0);
    }
  }

  // ---- epilogue ----
  float* ob = out + ((size_t)b * S_ + i * 128 + roff) * H_;
  #pragma unroll
  for (int tm = 0; tm < 2; tm++)
    #pragma unroll
    for (int tn = 0; tn < 4; tn++)
      #pragma unroll
      for (int r4 = 0; r4 < 4; r4++){
        int row = wrow + tm * 16 + lq * 4 + r4;
        int col = wcol + tn * 16 + lr;
        ob[(size_t)row * H_ + col] = acc[tm][tn][r4];
      }
}

// ---------------------------------------------------------------------------
extern "C" void kernel_launch(void* const* d_in, const int* in_sizes, int n_in,
                              void* d_out, int out_size, void* d_ws, size_t ws_size,
                              hipStream_t stream) {
  // setup_inputs order: key, query, value, W_Q, W_K, W_V (all fp32)
  const float* key   = (const float*)d_in[0];
  const float* query = (const float*)d_in[1];
  const float* value = (const float*)d_in[2];
  const float* WQ    = (const float*)d_in[3];
  const float* WK    = (const float*)d_in[4];
  const float* WV    = (const float*)d_in[5];
  float* out = (float*)d_out;

  char* w = (char*)d_ws;
  short* WtQ = (short*)(w + 0);                       // 3 x 256 KB
  short* WtK = (short*)(w + 262144);
  short* WtV = (short*)(w + 524288);
  size_t o = 786432;
  short* q  = (short*)(w + o); o += 4194304;          // (B,S,H) bf16
  short* k  = (short*)(w + o); o += 4194304;
  short* v  = (short*)(w + o); o += 4194304;
  short* kT = (short*)(w + o); o += 4194304;          // (B,H,S) bf16
  short* vT = (short*)(w + o); o += 4194304;
  float* M  = (float*)(w + o); o += 8388608;          // (B,NC,128,128) f32
  short* Shi= (short*)(w + o); o += 4194304;          // exclusive prefix, bf16 hi
  short* Slo= (short*)(w + o); o += 4194304;          // bf16 residual

  wt_kernel   <<<dim3(32, 4, 3),       256, 0, stream>>>(WQ, WK, WV, WtQ, WtK, WtV);
  proj_kernel <<<dim3(256, 3),         256, 0, stream>>>(query, key, value,
                                                         WtQ, WtK, WtV, q, k, v);
  transpose2  <<<dim3(64, 4, 16),      256, 0, stream>>>(k, v, kT, vT);
  chunk_state <<<dim3(NC_, B_),        256, 0, stream>>>(vT, kT, M);
  prefix_state<<<dim3(16, B_),         256, 0, stream>>>(M, Shi, Slo);
  passC       <<<dim3(NC_, 2, B_),     256, 0, stream>>>(q, k, vT, Shi, Slo, out);
}

// Round 4
// 248.786 us; speedup vs baseline: 1.1702x; 1.1702x over previous
//
#include <hip/hip_runtime.h>
#include <cstdint>

#define B_  8
#define S_  2048
#define E_  1024
#define H_  128
#define NC_ 16          // chunks per sequence (S_/128)

typedef __attribute__((ext_vector_type(8))) short bf16x8;
typedef __attribute__((ext_vector_type(4))) float f32x4;

__device__ __forceinline__ short f2bf(float f){
  uint32_t u = __builtin_bit_cast(uint32_t, f);
  u = (u + 0x7fffu + ((u >> 16) & 1u)) >> 16;   // RNE
  return (short)u;
}
__device__ __forceinline__ float bf2f(short s){
  uint32_t u = ((uint32_t)(uint16_t)s) << 16;
  return __builtin_bit_cast(float, u);
}
__device__ __forceinline__ void load_lds16(const void* g, void* l){
  __builtin_amdgcn_global_load_lds(
    (const __attribute__((address_space(1))) void*)g,
    (__attribute__((address_space(3))) void*)l, 16, 0, 0);
}

// ---------------------------------------------------------------------------
// Kernel 1: W (E,H) f32 -> Wt (H,E) bf16, LDS-tiled transpose
// ---------------------------------------------------------------------------
__global__ __launch_bounds__(256) void wt_kernel(
    const float* __restrict__ WQ, const float* __restrict__ WK,
    const float* __restrict__ WV,
    short* __restrict__ WtQ, short* __restrict__ WtK, short* __restrict__ WtV)
{
  int which = blockIdx.z;
  const float* W = which == 0 ? WQ : which == 1 ? WK : WV;
  short* Wt      = which == 0 ? WtQ : which == 1 ? WtK : WtV;
  int k0 = blockIdx.x * 32, n0 = blockIdx.y * 32;
  __shared__ float t[32][33];
  int tx = threadIdx.x & 31, ty = threadIdx.x >> 5;
  #pragma unroll
  for (int i = 0; i < 4; i++)
    t[ty + i * 8][tx] = W[(size_t)(k0 + ty + i * 8) * H_ + n0 + tx];
  __syncthreads();
  #pragma unroll
  for (int i = 0; i < 4; i++)
    Wt[(size_t)(n0 + ty + i * 8) * E_ + k0 + tx] = f2bf(t[tx][ty + i * 8]);
}

// ---------------------------------------------------------------------------
// Kernel 2: projections, 64-row strips (grid 256x3 = 768 blocks, 3/CU).
// Wave owns 16 rows x 128 cols. A: f32 direct global->regs (reg dbuf).
// B: bf16 via padded LDS (stride 40 shorts, uniform banks), LDS dbuf,
// ONE barrier per BK=32 step. Each thread stages 16 shorts = 2x bf16x8
// (row tid>>1, half (tid&1)).  Epilogue writes q / k+kT / vT.
// ---------------------------------------------------------------------------
__global__ __launch_bounds__(256) void proj_kernel(
    const float* __restrict__ Xq, const float* __restrict__ Xk,
    const float* __restrict__ Xv,
    const short* __restrict__ Wtq, const short* __restrict__ Wtk,
    const short* __restrict__ Wtv,
    short* __restrict__ q, short* __restrict__ k,
    short* __restrict__ kT, short* __restrict__ vT)
{
  int which = blockIdx.y;
  const float* X  = which == 0 ? Xq  : which == 1 ? Xk  : Xv;
  const short* Wt = which == 0 ? Wtq : which == 1 ? Wtk : Wtv;

  int tid = threadIdx.x, lane = tid & 63, wave = tid >> 6;
  int lr = lane & 15, lq = lane >> 4;
  int rowbase = blockIdx.x * 64 + wave * 16;   // wave's 16 rows

  __shared__ short Bs[2][128 * 40];            // padded stride 40

  const float* xr = X + (size_t)(rowbase + lr) * E_ + lq * 8;
  // B staging: thread t -> row t>>1, 16-short half (t&1)*16 (two bf16x8)
  int bn = tid >> 1, bc = (tid & 1) * 16;
  const short* wsrc = Wt + (size_t)bn * E_ + bc;

  f32x4 acc[8];
  #pragma unroll
  for (int tn = 0; tn < 8; tn++) acc[tn] = (f32x4){0.f, 0.f, 0.f, 0.f};

  // preload stage 0
  f32x4 alo = *(const f32x4*)xr;
  f32x4 ahi = *(const f32x4*)(xr + 4);
  *(bf16x8*)(&Bs[0][bn * 40 + bc])     = *(const bf16x8*)wsrc;
  *(bf16x8*)(&Bs[0][bn * 40 + bc + 8]) = *(const bf16x8*)(wsrc + 8);
  __syncthreads();

  int p = 0;
  for (int k0 = 0; k0 < E_; k0 += 32){
    bool more = (k0 + 32) < E_;
    f32x4 nlo, nhi; bf16x8 nb0, nb1;
    if (more){
      nlo = *(const f32x4*)(xr + k0 + 32);
      nhi = *(const f32x4*)(xr + k0 + 36);
      nb0 = *(const bf16x8*)(wsrc + k0 + 32);
      nb1 = *(const bf16x8*)(wsrc + k0 + 40);
    }
    bf16x8 a;
    #pragma unroll
    for (int j = 0; j < 4; j++){ a[j] = f2bf(alo[j]); a[4 + j] = f2bf(ahi[j]); }
    #pragma unroll
    for (int tn = 0; tn < 8; tn++){
      bf16x8 bfr = *(const bf16x8*)(&Bs[p][(tn * 16 + lr) * 40 + lq * 8]);
      acc[tn] = __builtin_amdgcn_mfma_f32_16x16x32_bf16(a, bfr, acc[tn], 0, 0, 0);
    }
    if (more){
      *(bf16x8*)(&Bs[p ^ 1][bn * 40 + bc])     = nb0;
      *(bf16x8*)(&Bs[p ^ 1][bn * 40 + bc + 8]) = nb1;
      __syncthreads();
      alo = nlo; ahi = nhi; p ^= 1;
    }
  }

  // ---- epilogue: C/D layout col=lane&15, row=(lane>>4)*4+reg ----
  if (which <= 1){
    short* P = which == 0 ? q : k;
    #pragma unroll
    for (int tn = 0; tn < 8; tn++)
      #pragma unroll
      for (int r4 = 0; r4 < 4; r4++)
        P[(size_t)(rowbase + lq * 4 + r4) * H_ + tn * 16 + lr] = f2bf(acc[tn][r4]);
  }
  if (which >= 1){
    short* T = which == 1 ? kT : vT;
    int b = rowbase >> 11, s = rowbase & 2047;
    #pragma unroll
    for (int tn = 0; tn < 8; tn++){
      union { short sh[4]; uint2 u; } pk;
      #pragma unroll
      for (int r4 = 0; r4 < 4; r4++) pk.sh[r4] = f2bf(acc[tn][r4]);
      *(uint2*)(T + ((size_t)b * H_ + tn * 16 + lr) * S_ + s + lq * 4) = pk.u;
    }
  }
}

// ---------------------------------------------------------------------------
// Kernel 3: per-chunk state M_j[h'][h] = sum_t V[t][h'] K[t][h], col halves
// grid (NC_, 2, B_) = 256 blocks
// ---------------------------------------------------------------------------
__global__ __launch_bounds__(256) void chunk_state(
    const short* __restrict__ vT, const short* __restrict__ kT,
    float* __restrict__ M)
{
  int j = blockIdx.x, half = blockIdx.y, b = blockIdx.z;
  int tid = threadIdx.x, lane = tid & 63, wave = tid >> 6;
  int wrow = wave * 32;
  int lr = lane & 15, lq = lane >> 4;

  __shared__ short As[128 * 32];   // vT rows 0..127 (DMA, unpadded)
  __shared__ short Bs[64 * 32];    // kT rows half*64.. (DMA, unpadded)

  const short* vtb = vT + (size_t)b * H_ * S_ + j * 128;
  const short* ktb = kT + (size_t)b * H_ * S_ + (size_t)half * 64 * S_ + j * 128;

  f32x4 acc[2][4];
  #pragma unroll
  for (int a = 0; a < 2; a++)
    #pragma unroll
    for (int c = 0; c < 4; c++) acc[a][c] = (f32x4){0.f, 0.f, 0.f, 0.f};

  for (int t0 = 0; t0 < 128; t0 += 32){
    __syncthreads();
    #pragma unroll
    for (int i = 0; i < 2; i++){
      int r = wave * 32 + i * 16 + (lane >> 2);
      int c = (lane & 3) * 8;
      load_lds16(vtb + (size_t)r * S_ + t0 + c,
                 (void*)(As + (wave * 32 + i * 16) * 32));
    }
    {
      int r = wave * 16 + (lane >> 2);
      int c = (lane & 3) * 8;
      load_lds16(ktb + (size_t)r * S_ + t0 + c,
                 (void*)(Bs + (wave * 16) * 32));
    }
    __syncthreads();
    bf16x8 af[2], bf[4];
    #pragma unroll
    for (int tm = 0; tm < 2; tm++)
      af[tm] = *(const bf16x8*)(As + (wrow + tm * 16 + lr) * 32 + lq * 8);
    #pragma unroll
    for (int tn = 0; tn < 4; tn++)
      bf[tn] = *(const bf16x8*)(Bs + (tn * 16 + lr) * 32 + lq * 8);
    #pragma unroll
    for (int tm = 0; tm < 2; tm++)
      #pragma unroll
      for (int tn = 0; tn < 4; tn++)
        acc[tm][tn] = __builtin_amdgcn_mfma_f32_16x16x32_bf16(
            af[tm], bf[tn], acc[tm][tn], 0, 0, 0);
  }

  float* mb = M + (size_t)(b * NC_ + j) * 16384;
  #pragma unroll
  for (int tm = 0; tm < 2; tm++)
    #pragma unroll
    for (int tn = 0; tn < 4; tn++)
      #pragma unroll
      for (int r4 = 0; r4 < 4; r4++){
        int row = wrow + tm * 16 + lq * 4 + r4;
        int col = half * 64 + tn * 16 + lr;
        mb[row * 128 + col] = acc[tm][tn][r4];
      }
}

// ---------------------------------------------------------------------------
// Kernel 4: exclusive prefix of M over chunks -> bf16 hi + residual lo
// ---------------------------------------------------------------------------
__global__ __launch_bounds__(256) void prefix_state(
    const float* __restrict__ M, short* __restrict__ Shi, short* __restrict__ Slo)
{
  int b = blockIdx.y;
  int idx = (blockIdx.x * 256 + threadIdx.x) * 4;
  float4 mv[NC_];
  #pragma unroll
  for (int j = 0; j < NC_; j++)
    mv[j] = *(const float4*)(M + (size_t)(b * NC_ + j) * 16384 + idx);

  float r0 = 0.f, r1 = 0.f, r2 = 0.f, r3 = 0.f;
  #pragma unroll
  for (int j = 0; j < NC_; j++){
    size_t o = (size_t)(b * NC_ + j) * 16384 + idx;
    short h0 = f2bf(r0), h1 = f2bf(r1), h2 = f2bf(r2), h3 = f2bf(r3);
    short l0 = f2bf(r0 - bf2f(h0)), l1 = f2bf(r1 - bf2f(h1));
    short l2 = f2bf(r2 - bf2f(h2)), l3 = f2bf(r3 - bf2f(h3));
    union { short s[4]; uint2 u; } ph, pl;
    ph.s[0] = h0; ph.s[1] = h1; ph.s[2] = h2; ph.s[3] = h3;
    pl.s[0] = l0; pl.s[1] = l1; pl.s[2] = l2; pl.s[3] = l3;
    *(uint2*)(Shi + o) = ph.u;
    *(uint2*)(Slo + o) = pl.u;
    r0 += mv[j].x; r1 += mv[j].y; r2 += mv[j].z; r3 += mv[j].w;
  }
}

// ---------------------------------------------------------------------------
// Kernel 5: per (b, chunk i, row-half): 64 rows of
//   O = (Q_i K_i^T . tril) V_i + Q_i (State_hi + State_lo)
// ---------------------------------------------------------------------------
__global__ __launch_bounds__(256) void passC(
    const short* __restrict__ qb, const short* __restrict__ kb,
    const short* __restrict__ vT, const short* __restrict__ Shi,
    const short* __restrict__ Slo, float* __restrict__ out)
{
  int i = blockIdx.x, half = blockIdx.y, b = blockIdx.z;
  int roff = half * 64;
  int tid = threadIdx.x, lane = tid & 63, wave = tid >> 6;
  int wrow = (wave >> 1) * 32, wcol = (wave & 1) * 64;
  int lr = lane & 15, lq = lane >> 4;

  __shared__ short Qs[64 * 136];    // padded stride 136
  __shared__ short Ss[64 * 136];
  __shared__ short Bsh[128 * 32];   // DMA staging (unpadded)

  const short* qbase = qb + ((size_t)b * S_ + i * 128 + roff) * H_;
  const short* kbase = kb + ((size_t)b * S_ + i * 128) * H_;
  const short* vtb   = vT + (size_t)b * H_ * S_ + i * 128;
  const short* shib  = Shi + (size_t)(b * NC_ + i) * 16384;
  const short* slob  = Slo + (size_t)(b * NC_ + i) * 16384;

  // stage 64 Q rows into padded LDS
  #pragma unroll
  for (int t = 0; t < 4; t++){
    int chunk = t * 256 + tid;           // 1024 chunks of 16B
    int s = chunk >> 4, c16 = chunk & 15;
    *(uint4*)(Qs + s * 136 + c16 * 8) =
        *(const uint4*)(qbase + s * H_ + c16 * 8);
  }

  f32x4 acc[2][4];
  #pragma unroll
  for (int a = 0; a < 2; a++)
    #pragma unroll
    for (int c = 0; c < 4; c++) acc[a][c] = (f32x4){0.f, 0.f, 0.f, 0.f};

  // ---- phase 1: S = Q_half K^T (k-dim = h) ----
  for (int h0 = 0; h0 < H_; h0 += 32){
    __syncthreads();
    #pragma unroll
    for (int t = 0; t < 2; t++){
      int r = wave * 32 + t * 16 + (lane >> 2);
      int c = (lane & 3) * 8;
      load_lds16(kbase + (size_t)r * H_ + h0 + c,
                 (void*)(Bsh + (wave * 32 + t * 16) * 32));
    }
    __syncthreads();
    bf16x8 af[2], bf[4];
    #pragma unroll
    for (int tm = 0; tm < 2; tm++)
      af[tm] = *(const bf16x8*)(Qs + (wrow + tm * 16 + lr) * 136 + h0 + lq * 8);
    #pragma unroll
    for (int tn = 0; tn < 4; tn++)
      bf[tn] = *(const bf16x8*)(Bsh + (wcol + tn * 16 + lr) * 32 + lq * 8);
    #pragma unroll
    for (int tm = 0; tm < 2; tm++)
      #pragma unroll
      for (int tn = 0; tn < 4; tn++)
        acc[tm][tn] = __builtin_amdgcn_mfma_f32_16x16x32_bf16(
            af[tm], bf[tn], acc[tm][tn], 0, 0, 0);
  }
  __syncthreads();

  // ---- phase 2: causal mask + bf16 -> Ss; zero acc for O ----
  #pragma unroll
  for (int tm = 0; tm < 2; tm++)
    #pragma unroll
    for (int tn = 0; tn < 4; tn++)
      #pragma unroll
      for (int r4 = 0; r4 < 4; r4++){
        int row = wrow + tm * 16 + lq * 4 + r4;     // local row in half
        int col = wcol + tn * 16 + lr;              // t index 0..127
        float vv = (col <= roff + row) ? acc[tm][tn][r4] : 0.f;
        Ss[row * 136 + col] = f2bf(vv);
      }
  #pragma unroll
  for (int a = 0; a < 2; a++)
    #pragma unroll
    for (int c = 0; c < 4; c++) acc[a][c] = (f32x4){0.f, 0.f, 0.f, 0.f};
  __syncthreads();

  // ---- phase 3a: O += S V (k-dim = t); B operand from vT rows ----
  for (int t0 = 0; t0 < 128; t0 += 32){
    __syncthreads();
    #pragma unroll
    for (int t = 0; t < 2; t++){
      int r = wave * 32 + t * 16 + (lane >> 2);
      int c = (lane & 3) * 8;
      load_lds16(vtb + (size_t)r * S_ + t0 + c,
                 (void*)(Bsh + (wave * 32 + t * 16) * 32));
    }
    __syncthreads();
    bf16x8 af[2], bf[4];
    #pragma unroll
    for (int tm = 0; tm < 2; tm++)
      af[tm] = *(const bf16x8*)(Ss + (wrow + tm * 16 + lr) * 136 + t0 + lq * 8);
    #pragma unroll
    for (int tn = 0; tn < 4; tn++)
      bf[tn] = *(const bf16x8*)(Bsh + (wcol + tn * 16 + lr) * 32 + lq * 8);
    #pragma unroll
    for (int tm = 0; tm < 2; tm++)
      #pragma unroll
      for (int tn = 0; tn < 4; tn++)
        acc[tm][tn] = __builtin_amdgcn_mfma_f32_16x16x32_bf16(
            af[tm], bf[tn], acc[tm][tn], 0, 0, 0);
  }

  // ---- phase 3b: O += Q * State (hi then lo residual), k-dim = h ----
  #pragma unroll
  for (int part = 0; part < 2; part++){
    const short* sb = part == 0 ? shib : slob;
    for (int h0 = 0; h0 < H_; h0 += 32){
      __syncthreads();
      #pragma unroll
      for (int t = 0; t < 2; t++){
        int r = wave * 32 + t * 16 + (lane >> 2);
        int c = (lane & 3) * 8;
        load_lds16(sb + (size_t)r * 128 + h0 + c,
                   (void*)(Bsh + (wave * 32 + t * 16) * 32));
      }
      __syncthreads();
      bf16x8 af[2], bf[4];
      #pragma unroll
      for (int tm = 0; tm < 2; tm++)
        af[tm] = *(const bf16x8*)(Qs + (wrow + tm * 16 + lr) * 136 + h0 + lq * 8);
      #pragma unroll
      for (int tn = 0; tn < 4; tn++)
        bf[tn] = *(const bf16x8*)(Bsh + (wcol + tn * 16 + lr) * 32 + lq * 8);
      #pragma unroll
      for (int tm = 0; tm < 2; tm++)
        #pragma unroll
        for (int tn = 0; tn < 4; tn++)
          acc[tm][tn] = __builtin_amdgcn_mfma_f32_16x16x32_bf16(
              af[tm], bf[tn], acc[tm][tn], 0, 0, 0);
    }
  }

  // ---- epilogue ----
  float* ob = out + ((size_t)b * S_ + i * 128 + roff) * H_;
  #pragma unroll
  for (int tm = 0; tm < 2; tm++)
    #pragma unroll
    for (int tn = 0; tn < 4; tn++)
      #pragma unroll
      for (int r4 = 0; r4 < 4; r4++){
        int row = wrow + tm * 16 + lq * 4 + r4;
        int col = wcol + tn * 16 + lr;
        ob[(size_t)row * H_ + col] = acc[tm][tn][r4];
      }
}

// ---------------------------------------------------------------------------
extern "C" void kernel_launch(void* const* d_in, const int* in_sizes, int n_in,
                              void* d_out, int out_size, void* d_ws, size_t ws_size,
                              hipStream_t stream) {
  // setup_inputs order: key, query, value, W_Q, W_K, W_V (all fp32)
  const float* key   = (const float*)d_in[0];
  const float* query = (const float*)d_in[1];
  const float* value = (const float*)d_in[2];
  const float* WQ    = (const float*)d_in[3];
  const float* WK    = (const float*)d_in[4];
  const float* WV    = (const float*)d_in[5];
  float* out = (float*)d_out;

  char* w = (char*)d_ws;
  short* WtQ = (short*)(w + 0);                       // 3 x 256 KB
  short* WtK = (short*)(w + 262144);
  short* WtV = (short*)(w + 524288);
  size_t o = 786432;
  short* q  = (short*)(w + o); o += 4194304;          // (B,S,H) bf16
  short* k  = (short*)(w + o); o += 4194304;
  short* kT = (short*)(w + o); o += 4194304;          // (B,H,S) bf16
  short* vT = (short*)(w + o); o += 4194304;
  float* M  = (float*)(w + o); o += 8388608;          // (B,NC,128,128) f32
  short* Shi= (short*)(w + o); o += 4194304;          // exclusive prefix, bf16 hi
  short* Slo= (short*)(w + o); o += 4194304;          // bf16 residual

  wt_kernel   <<<dim3(32, 4, 3),       256, 0, stream>>>(WQ, WK, WV, WtQ, WtK, WtV);
  proj_kernel <<<dim3(256, 3),         256, 0, stream>>>(query, key, value,
                                                         WtQ, WtK, WtV, q, k, kT, vT);
  chunk_state <<<dim3(NC_, 2, B_),     256, 0, stream>>>(vT, kT, M);
  prefix_state<<<dim3(16, B_),         256, 0, stream>>>(M, Shi, Slo);
  passC       <<<dim3(NC_, 2, B_),     256, 0, stream>>>(q, k, vT, Shi, Slo, out);
}

// Round 5
// 228.563 us; speedup vs baseline: 1.2737x; 1.0885x over previous
//
#include <hip/hip_runtime.h>
#include <cstdint>

#define B_  8
#define S_  2048
#define E_  1024
#define H_  128
#define NC_ 16          // chunks per sequence (S_/128)

typedef __attribute__((ext_vector_type(8))) short bf16x8;
typedef __attribute__((ext_vector_type(4))) float f32x4;

__device__ __forceinline__ short f2bf(float f){
  uint32_t u = __builtin_bit_cast(uint32_t, f);
  u = (u + 0x7fffu + ((u >> 16) & 1u)) >> 16;   // RNE
  return (short)u;
}
__device__ __forceinline__ float bf2f(short s){
  uint32_t u = ((uint32_t)(uint16_t)s) << 16;
  return __builtin_bit_cast(float, u);
}

// ---------------------------------------------------------------------------
// Kernel 1: W (E,H) f32 -> Wt (H,E) bf16, LDS-tiled transpose
// ---------------------------------------------------------------------------
__global__ __launch_bounds__(256) void wt_kernel(
    const float* __restrict__ WQ, const float* __restrict__ WK,
    const float* __restrict__ WV,
    short* __restrict__ WtQ, short* __restrict__ WtK, short* __restrict__ WtV)
{
  int which = blockIdx.z;
  const float* W = which == 0 ? WQ : which == 1 ? WK : WV;
  short* Wt      = which == 0 ? WtQ : which == 1 ? WtK : WtV;
  int k0 = blockIdx.x * 32, n0 = blockIdx.y * 32;
  __shared__ float t[32][33];
  int tx = threadIdx.x & 31, ty = threadIdx.x >> 5;
  #pragma unroll
  for (int i = 0; i < 4; i++)
    t[ty + i * 8][tx] = W[(size_t)(k0 + ty + i * 8) * H_ + n0 + tx];
  __syncthreads();
  #pragma unroll
  for (int i = 0; i < 4; i++)
    Wt[(size_t)(n0 + ty + i * 8) * E_ + k0 + tx] = f2bf(t[tx][ty + i * 8]);
}

// ---------------------------------------------------------------------------
// Kernel 2 v3: projections. 64-row blocks (grid 256x3), 34.8KB LDS ->
// 4 blocks/CU (16 waves). K processed in 8 chunks of 128; inside a chunk
// the 4 k-steps are BARRIER-FREE (B resident in padded LDS, A in regs).
// One combined vm drain per chunk instead of one per 32-k step.
// ---------------------------------------------------------------------------
__global__ __launch_bounds__(256) void proj_kernel(
    const float* __restrict__ Xq, const float* __restrict__ Xk,
    const float* __restrict__ Xv,
    const short* __restrict__ Wtq, const short* __restrict__ Wtk,
    const short* __restrict__ Wtv,
    short* __restrict__ q, short* __restrict__ k,
    short* __restrict__ kT, short* __restrict__ vT)
{
  int which = blockIdx.y;
  const float* X  = which == 0 ? Xq  : which == 1 ? Xk  : Xv;
  const short* Wt = which == 0 ? Wtq : which == 1 ? Wtk : Wtv;

  int tid = threadIdx.x, lane = tid & 63, wave = tid >> 6;
  int lr = lane & 15, lq = lane >> 4;
  int rowbase = blockIdx.x * 64 + wave * 16;   // wave's 16 rows

  __shared__ short Bs[128 * 136];              // padded stride 136 (34.8 KB)

  const float* xr = X + (size_t)(rowbase + lr) * E_ + lq * 8;

  f32x4 acc[8];
  #pragma unroll
  for (int tn = 0; tn < 8; tn++) acc[tn] = (f32x4){0.f, 0.f, 0.f, 0.f};

  for (int kc = 0; kc < 8; kc++){              // 128-k chunks
    if (kc) __syncthreads();                   // prev chunk's reads done
    // volley: stage B chunk, 128 rows x 128 shorts; 8 x 16B per thread
    #pragma unroll
    for (int v = 0; v < 8; v++){
      int c = v * 256 + tid;
      int n = c >> 4, off = (c & 15) * 8;
      *(bf16x8*)(&Bs[n * 136 + off]) =
          *(const bf16x8*)(Wt + (size_t)n * E_ + kc * 128 + off);
    }
    // A for the whole chunk: 8 x f32x4 in flight
    f32x4 ar[8];
    #pragma unroll
    for (int s = 0; s < 4; s++){
      ar[2 * s]     = *(const f32x4*)(xr + kc * 128 + s * 32);
      ar[2 * s + 1] = *(const f32x4*)(xr + kc * 128 + s * 32 + 4);
    }
    __syncthreads();                           // single drain per chunk
    #pragma unroll
    for (int s = 0; s < 4; s++){
      bf16x8 a;
      #pragma unroll
      for (int j = 0; j < 4; j++){
        a[j] = f2bf(ar[2 * s][j]); a[4 + j] = f2bf(ar[2 * s + 1][j]);
      }
      #pragma unroll
      for (int tn = 0; tn < 8; tn++){
        bf16x8 bfr = *(const bf16x8*)(&Bs[(tn * 16 + lr) * 136 + s * 32 + lq * 8]);
        acc[tn] = __builtin_amdgcn_mfma_f32_16x16x32_bf16(a, bfr, acc[tn], 0, 0, 0);
      }
    }
  }

  // ---- epilogue: C/D layout col=lane&15, row=(lane>>4)*4+reg ----
  if (which <= 1){
    short* P = which == 0 ? q : k;
    #pragma unroll
    for (int tn = 0; tn < 8; tn++)
      #pragma unroll
      for (int r4 = 0; r4 < 4; r4++)
        P[(size_t)(rowbase + lq * 4 + r4) * H_ + tn * 16 + lr] = f2bf(acc[tn][r4]);
  }
  if (which >= 1){
    short* T = which == 1 ? kT : vT;
    int b = rowbase >> 11, s = rowbase & 2047;
    #pragma unroll
    for (int tn = 0; tn < 8; tn++){
      union { short sh[4]; uint2 u; } pk;
      #pragma unroll
      for (int r4 = 0; r4 < 4; r4++) pk.sh[r4] = f2bf(acc[tn][r4]);
      *(uint2*)(T + ((size_t)b * H_ + tn * 16 + lr) * S_ + s + lq * 4) = pk.u;
    }
  }
}

// ---------------------------------------------------------------------------
// Kernel 3 v2: per-chunk state M_j[h'][h] = sum_t V[t][h'] K[t][h], col halves.
// Full tiles staged once (padded 136), ONE barrier, 4 barrier-free t-steps.
// ---------------------------------------------------------------------------
__global__ __launch_bounds__(256) void chunk_state(
    const short* __restrict__ vT, const short* __restrict__ kT,
    float* __restrict__ M)
{
  int j = blockIdx.x, half = blockIdx.y, b = blockIdx.z;
  int tid = threadIdx.x, lane = tid & 63, wave = tid >> 6;
  int wrow = wave * 32;
  int lr = lane & 15, lq = lane >> 4;

  __shared__ short As[128 * 136];   // vT rows (h' x t), 34.8 KB
  __shared__ short Bs[64 * 136];    // kT rows half (h x t), 17.4 KB

  const short* vtb = vT + (size_t)b * H_ * S_ + j * 128;
  const short* ktb = kT + (size_t)b * H_ * S_ + (size_t)half * 64 * S_ + j * 128;

  // volleys: A 2048 chunks (8/thread), B 1024 chunks (4/thread)
  #pragma unroll
  for (int v = 0; v < 8; v++){
    int c = v * 256 + tid;
    int r = c >> 4, off = (c & 15) * 8;
    *(bf16x8*)(&As[r * 136 + off]) = *(const bf16x8*)(vtb + (size_t)r * S_ + off);
  }
  #pragma unroll
  for (int v = 0; v < 4; v++){
    int c = v * 256 + tid;
    int r = c >> 4, off = (c & 15) * 8;
    *(bf16x8*)(&Bs[r * 136 + off]) = *(const bf16x8*)(ktb + (size_t)r * S_ + off);
  }
  __syncthreads();

  f32x4 acc[2][4];
  #pragma unroll
  for (int a = 0; a < 2; a++)
    #pragma unroll
    for (int c = 0; c < 4; c++) acc[a][c] = (f32x4){0.f, 0.f, 0.f, 0.f};

  #pragma unroll
  for (int s = 0; s < 4; s++){
    int t0 = s * 32;
    bf16x8 af[2], bf[4];
    #pragma unroll
    for (int tm = 0; tm < 2; tm++)
      af[tm] = *(const bf16x8*)(&As[(wrow + tm * 16 + lr) * 136 + t0 + lq * 8]);
    #pragma unroll
    for (int tn = 0; tn < 4; tn++)
      bf[tn] = *(const bf16x8*)(&Bs[(tn * 16 + lr) * 136 + t0 + lq * 8]);
    #pragma unroll
    for (int tm = 0; tm < 2; tm++)
      #pragma unroll
      for (int tn = 0; tn < 4; tn++)
        acc[tm][tn] = __builtin_amdgcn_mfma_f32_16x16x32_bf16(
            af[tm], bf[tn], acc[tm][tn], 0, 0, 0);
  }

  float* mb = M + (size_t)(b * NC_ + j) * 16384;
  #pragma unroll
  for (int tm = 0; tm < 2; tm++)
    #pragma unroll
    for (int tn = 0; tn < 4; tn++)
      #pragma unroll
      for (int r4 = 0; r4 < 4; r4++){
        int row = wrow + tm * 16 + lq * 4 + r4;
        int col = half * 64 + tn * 16 + lr;
        mb[row * 128 + col] = acc[tm][tn][r4];
      }
}

// ---------------------------------------------------------------------------
// Kernel 4: exclusive prefix of M over chunks -> bf16 hi + residual lo
// ---------------------------------------------------------------------------
__global__ __launch_bounds__(256) void prefix_state(
    const float* __restrict__ M, short* __restrict__ Shi, short* __restrict__ Slo)
{
  int b = blockIdx.y;
  int idx = (blockIdx.x * 256 + threadIdx.x) * 4;
  float4 mv[NC_];
  #pragma unroll
  for (int j = 0; j < NC_; j++)
    mv[j] = *(const float4*)(M + (size_t)(b * NC_ + j) * 16384 + idx);

  float r0 = 0.f, r1 = 0.f, r2 = 0.f, r3 = 0.f;
  #pragma unroll
  for (int j = 0; j < NC_; j++){
    size_t o = (size_t)(b * NC_ + j) * 16384 + idx;
    short h0 = f2bf(r0), h1 = f2bf(r1), h2 = f2bf(r2), h3 = f2bf(r3);
    short l0 = f2bf(r0 - bf2f(h0)), l1 = f2bf(r1 - bf2f(h1));
    short l2 = f2bf(r2 - bf2f(h2)), l3 = f2bf(r3 - bf2f(h3));
    union { short s[4]; uint2 u; } ph, pl;
    ph.s[0] = h0; ph.s[1] = h1; ph.s[2] = h2; ph.s[3] = h3;
    pl.s[0] = l0; pl.s[1] = l1; pl.s[2] = l2; pl.s[3] = l3;
    *(uint2*)(Shi + o) = ph.u;
    *(uint2*)(Slo + o) = pl.u;
    r0 += mv[j].x; r1 += mv[j].y; r2 += mv[j].z; r3 += mv[j].w;
  }
}

// ---------------------------------------------------------------------------
// Kernel 5 v2: per (b, chunk i, row-half): 64 rows of
//   O = (Q_i K_i^T . tril) V_i + Q_i (State_hi + State_lo)
// Q a-frags live in registers (loaded direct from global). One shared
// staging buffer Bt (128x136) reused for K / V / Shi / Slo; 6 barriers total.
// ---------------------------------------------------------------------------
__global__ __launch_bounds__(256) void passC(
    const short* __restrict__ qb, const short* __restrict__ kb,
    const short* __restrict__ vT, const short* __restrict__ Shi,
    const short* __restrict__ Slo, float* __restrict__ out)
{
  int i = blockIdx.x, half = blockIdx.y, b = blockIdx.z;
  int roff = half * 64;
  int tid = threadIdx.x, lane = tid & 63, wave = tid >> 6;
  int wrow = (wave >> 1) * 32, wcol = (wave & 1) * 64;
  int lr = lane & 15, lq = lane >> 4;

  __shared__ short Ss[64 * 136];    // masked scores, padded
  __shared__ short Bt[128 * 136];   // staging: K, then V, then Shi, then Slo

  const short* qbase = qb + ((size_t)b * S_ + i * 128 + roff) * H_;
  const short* kbase = kb + ((size_t)b * S_ + i * 128) * H_;
  const short* vtb   = vT + (size_t)b * H_ * S_ + i * 128;
  const short* shib  = Shi + (size_t)(b * NC_ + i) * 16384;
  const short* slob  = Slo + (size_t)(b * NC_ + i) * 16384;

  // Q a-frags to registers: aq[tm][hs], A[row=lr][k=lq*8..] per 16x16x32
  bf16x8 aq[2][4];
  #pragma unroll
  for (int tm = 0; tm < 2; tm++)
    #pragma unroll
    for (int hs = 0; hs < 4; hs++)
      aq[tm][hs] = *(const bf16x8*)(
          qbase + (size_t)(wrow + tm * 16 + lr) * H_ + hs * 32 + lq * 8);

  // stage K-tile (128 rows x 128 h)
  #pragma unroll
  for (int v = 0; v < 8; v++){
    int c = v * 256 + tid;
    int r = c >> 4, off = (c & 15) * 8;
    *(bf16x8*)(&Bt[r * 136 + off]) = *(const bf16x8*)(kbase + (size_t)r * H_ + off);
  }
  __syncthreads();

  f32x4 acc[2][4];
  #pragma unroll
  for (int a = 0; a < 2; a++)
    #pragma unroll
    for (int c = 0; c < 4; c++) acc[a][c] = (f32x4){0.f, 0.f, 0.f, 0.f};

  // ---- phase 1: S = Q_half K^T, barrier-free ----
  #pragma unroll
  for (int hs = 0; hs < 4; hs++){
    bf16x8 bf[4];
    #pragma unroll
    for (int tn = 0; tn < 4; tn++)
      bf[tn] = *(const bf16x8*)(&Bt[(wcol + tn * 16 + lr) * 136 + hs * 32 + lq * 8]);
    #pragma unroll
    for (int tm = 0; tm < 2; tm++)
      #pragma unroll
      for (int tn = 0; tn < 4; tn++)
        acc[tm][tn] = __builtin_amdgcn_mfma_f32_16x16x32_bf16(
            aq[tm][hs], bf[tn], acc[tm][tn], 0, 0, 0);
  }
  __syncthreads();   // phase1 reads done; Bt may be overwritten

  // ---- phase 2: mask + bf16 -> Ss; stage V-tile into Bt ----
  #pragma unroll
  for (int tm = 0; tm < 2; tm++)
    #pragma unroll
    for (int tn = 0; tn < 4; tn++)
      #pragma unroll
      for (int r4 = 0; r4 < 4; r4++){
        int row = wrow + tm * 16 + lq * 4 + r4;     // local row in half
        int col = wcol + tn * 16 + lr;              // t index 0..127
        float vv = (col <= roff + row) ? acc[tm][tn][r4] : 0.f;
        Ss[row * 136 + col] = f2bf(vv);
      }
  #pragma unroll
  for (int v = 0; v < 8; v++){
    int c = v * 256 + tid;
    int r = c >> 4, off = (c & 15) * 8;
    *(bf16x8*)(&Bt[r * 136 + off]) = *(const bf16x8*)(vtb + (size_t)r * S_ + off);
  }
  #pragma unroll
  for (int a = 0; a < 2; a++)
    #pragma unroll
    for (int c = 0; c < 4; c++) acc[a][c] = (f32x4){0.f, 0.f, 0.f, 0.f};
  __syncthreads();

  // ---- phase 3a: O += S V, barrier-free ----
  #pragma unroll
  for (int s = 0; s < 4; s++){
    int t0 = s * 32;
    bf16x8 af[2], bf[4];
    #pragma unroll
    for (int tm = 0; tm < 2; tm++)
      af[tm] = *(const bf16x8*)(&Ss[(wrow + tm * 16 + lr) * 136 + t0 + lq * 8]);
    #pragma unroll
    for (int tn = 0; tn < 4; tn++)
      bf[tn] = *(const bf16x8*)(&Bt[(wcol + tn * 16 + lr) * 136 + t0 + lq * 8]);
    #pragma unroll
    for (int tm = 0; tm < 2; tm++)
      #pragma unroll
      for (int tn = 0; tn < 4; tn++)
        acc[tm][tn] = __builtin_amdgcn_mfma_f32_16x16x32_bf16(
            af[tm], bf[tn], acc[tm][tn], 0, 0, 0);
  }
  __syncthreads();

  // ---- phase 3b: O += Q * State (hi then lo residual) ----
  #pragma unroll
  for (int part = 0; part < 2; part++){
    const short* sb = part == 0 ? shib : slob;
    #pragma unroll
    for (int v = 0; v < 8; v++){
      int c = v * 256 + tid;
      int r = c >> 4, off = (c & 15) * 8;
      *(bf16x8*)(&Bt[r * 136 + off]) = *(const bf16x8*)(sb + (size_t)r * 128 + off);
    }
    __syncthreads();
    #pragma unroll
    for (int hs = 0; hs < 4; hs++){
      bf16x8 bf[4];
      #pragma unroll
      for (int tn = 0; tn < 4; tn++)
        bf[tn] = *(const bf16x8*)(&Bt[(wcol + tn * 16 + lr) * 136 + hs * 32 + lq * 8]);
      #pragma unroll
      for (int tm = 0; tm < 2; tm++)
        #pragma unroll
        for (int tn = 0; tn < 4; tn++)
          acc[tm][tn] = __builtin_amdgcn_mfma_f32_16x16x32_bf16(
              aq[tm][hs], bf[tn], acc[tm][tn], 0, 0, 0);
    }
    if (part == 0) __syncthreads();
  }

  // ---- epilogue ----
  float* ob = out + ((size_t)b * S_ + i * 128 + roff) * H_;
  #pragma unroll
  for (int tm = 0; tm < 2; tm++)
    #pragma unroll
    for (int tn = 0; tn < 4; tn++)
      #pragma unroll
      for (int r4 = 0; r4 < 4; r4++){
        int row = wrow + tm * 16 + lq * 4 + r4;
        int col = wcol + tn * 16 + lr;
        ob[(size_t)row * H_ + col] = acc[tm][tn][r4];
      }
}

// ---------------------------------------------------------------------------
extern "C" void kernel_launch(void* const* d_in, const int* in_sizes, int n_in,
                              void* d_out, int out_size, void* d_ws, size_t ws_size,
                              hipStream_t stream) {
  // setup_inputs order: key, query, value, W_Q, W_K, W_V (all fp32)
  const float* key   = (const float*)d_in[0];
  const float* query = (const float*)d_in[1];
  const float* value = (const float*)d_in[2];
  const float* WQ    = (const float*)d_in[3];
  const float* WK    = (const float*)d_in[4];
  const float* WV    = (const float*)d_in[5];
  float* out = (float*)d_out;

  char* w = (char*)d_ws;
  short* WtQ = (short*)(w + 0);                       // 3 x 256 KB
  short* WtK = (short*)(w + 262144);
  short* WtV = (short*)(w + 524288);
  size_t o = 786432;
  short* q  = (short*)(w + o); o += 4194304;          // (B,S,H) bf16
  short* k  = (short*)(w + o); o += 4194304;
  short* kT = (short*)(w + o); o += 4194304;          // (B,H,S) bf16
  short* vT = (short*)(w + o); o += 4194304;
  float* M  = (float*)(w + o); o += 8388608;          // (B,NC,128,128) f32
  short* Shi= (short*)(w + o); o += 4194304;          // exclusive prefix, bf16 hi
  short* Slo= (short*)(w + o); o += 4194304;          // bf16 residual

  wt_kernel   <<<dim3(32, 4, 3),       256, 0, stream>>>(WQ, WK, WV, WtQ, WtK, WtV);
  proj_kernel <<<dim3(256, 3),         256, 0, stream>>>(query, key, value,
                                                         WtQ, WtK, WtV, q, k, kT, vT);
  chunk_state <<<dim3(NC_, 2, B_),     256, 0, stream>>>(vT, kT, M);
  prefix_state<<<dim3(16, B_),         256, 0, stream>>>(M, Shi, Slo);
  passC       <<<dim3(NC_, 2, B_),     256, 0, stream>>>(q, k, vT, Shi, Slo, out);
}